// Round 1
// 136.419 us; speedup vs baseline: 1.0832x; 1.0832x over previous
//
#include <hip/hip_runtime.h>
#include <stdint.h>
#include <math.h>

// Problem constants (from reference: B=2048, D=512, TAU=0.5)
#define DIM       512
#define NROWS     8192      // 4*B
#define HALF_ROWS 4096      // 2*B
#define NT        32        // 8192 / 256 tiles per side
#define NTRI      528       // NT*(NT+1)/2 upper-triangle blocks

typedef float  floatx4 __attribute__((ext_vector_type(4)));
typedef __bf16 bf16x8  __attribute__((ext_vector_type(8)));

__device__ __forceinline__ void async_copy16(const unsigned short* g, unsigned short* l) {
    __builtin_amdgcn_global_load_lds(
        (const __attribute__((address_space(1))) uint32_t*)(g),
        (__attribute__((address_space(3))) uint32_t*)(l),
        16, 0, 0);
}

// L2-normalize rows of [emb_i; emb_j] and store as bf16 into rep[8192][512].
// 4 rows per block (one per wave); lane handles 8 consecutive floats.
// Also zero-inits the two ws accumulators (block 0) — replaces init_ws kernel.
__global__ __launch_bounds__(256) void normalize_kernel(
    const float* __restrict__ emb_i, const float* __restrict__ emb_j,
    unsigned short* __restrict__ rep, double* __restrict__ ws)
{
    if (blockIdx.x == 0 && threadIdx.x == 0) { ws[0] = 0.0; ws[1] = 0.0; }
    const int wave = threadIdx.x >> 6;
    const int lane = threadIdx.x & 63;
    const int row  = blockIdx.x * 4 + wave;
    const float* src = (row < HALF_ROWS) ? (emb_i + (size_t)row * DIM)
                                         : (emb_j + (size_t)(row - HALF_ROWS) * DIM);
    const int c = lane * 8;
    float4 v0 = *(const float4*)(src + c);
    float4 v1 = *(const float4*)(src + c + 4);
    float s = v0.x*v0.x + v0.y*v0.y + v0.z*v0.z + v0.w*v0.w
            + v1.x*v1.x + v1.y*v1.y + v1.z*v1.z + v1.w*v1.w;
    #pragma unroll
    for (int off = 32; off; off >>= 1) s += __shfl_xor(s, off, 64);
    const float nrm = sqrtf(s);
    const float inv = 1.0f / fmaxf(nrm, 1e-12f);
    float f[8] = {v0.x*inv, v0.y*inv, v0.z*inv, v0.w*inv,
                  v1.x*inv, v1.y*inv, v1.z*inv, v1.w*inv};
    union { unsigned short h[8]; uint4 u; } pk;
    #pragma unroll
    for (int t = 0; t < 8; ++t) {   // fp32 -> bf16 round-to-nearest-even
        uint32_t b = __float_as_uint(f[t]);
        b += 0x7FFFu + ((b >> 16) & 1u);
        pk.h[t] = (unsigned short)(b >> 16);
    }
    *(uint4*)(rep + (size_t)row * DIM + c) = pk.u;
}

// Stage one 128x64 bf16 half-tile (16 KB) into LDS, 2 x 16B per thread.
// LDS destination is LINEAR (global_load_lds requirement); the bank-conflict
// swizzle (byte ^= (row&7)<<4) is applied by permuting the GLOBAL source
// column slot (rule: both-sides-or-neither; XOR is its own inverse).
__device__ __forceinline__ void stage_half(const unsigned short* __restrict__ rep,
    int rowbase, int k0, unsigned short* lds, int tid)
{
    #pragma unroll
    for (int l = 0; l < 2; ++l) {
        const int ch  = l * 512 + tid;          // 1024 chunks of 16 B
        const int row = ch >> 3;                // 8 chunks per 64-col row
        const int s   = ch & 7;
        const int col = (s ^ (row & 7)) << 3;   // pre-swizzled source slot
        async_copy16(rep + (size_t)(rowbase + row) * DIM + (k0 + col), lds + ch * 8);
    }
}

#define PH_BAR1() do { __builtin_amdgcn_s_barrier(); \
    asm volatile("s_waitcnt lgkmcnt(0)" ::: "memory"); \
    __builtin_amdgcn_sched_barrier(0); } while (0)

#define PH_BAR2() do { __builtin_amdgcn_s_barrier(); \
    __builtin_amdgcn_sched_barrier(0); } while (0)

#define WAIT_VM(N) asm volatile("s_waitcnt vmcnt(" #N ")" ::: "memory")

// Read A-fragments for one 64-row quadrant half (MH in {0,1}), both k-halves.
#define LOAD_A(BUF, MH) do { const unsigned short* Ah_ = sA[BUF][wm]; \
    _Pragma("unroll") for (int mt = 0; mt < 4; ++mt) { \
        const int r_ = (MH)*64 + mt*16 + m; \
        a[mt][0] = *(const bf16x8*)((const char*)Ah_ + r_*128 + koff0); \
        a[mt][1] = *(const bf16x8*)((const char*)Ah_ + r_*128 + koff1); } } while (0)

// Read B-fragments for one 32-col quadrant half (NS in {0,1}) into DST.
#define LOAD_B(BUF, NS, DST) do { const unsigned short* Bh_ = sB[BUF][wn >> 1]; \
    _Pragma("unroll") for (int nt = 0; nt < 2; ++nt) { \
        const int r_ = (wn & 1)*64 + ((NS)*2 + nt)*16 + m; \
        DST[nt][0] = *(const bf16x8*)((const char*)Bh_ + r_*128 + koff0); \
        DST[nt][1] = *(const bf16x8*)((const char*)Bh_ + r_*128 + koff1); } } while (0)

// One phase's MFMA cluster: 4 m-frags x 2 n-frags x 2 k-halves = 16 MFMA.
#define MFMA_Q(MH, NS, BB) do { \
    __builtin_amdgcn_s_setprio(1); \
    _Pragma("unroll") for (int mt = 0; mt < 4; ++mt) \
      _Pragma("unroll") for (int nt = 0; nt < 2; ++nt) \
        _Pragma("unroll") for (int kk = 0; kk < 2; ++kk) \
          acc[(MH)*4 + mt][(NS)*2 + nt] = __builtin_amdgcn_mfma_f32_16x16x32_bf16( \
              a[mt][kk], BB[nt][kk], acc[(MH)*4 + mt][(NS)*2 + nt], 0, 0, 0); \
    __builtin_amdgcn_s_setprio(0); } while (0)

// 8-phase double-buffered 256x256 Gram tile + fused exp/band reduction.
// 8 waves (2M x 4N), per-wave 128x64 output; BK=64; counted vmcnt(4).
__global__ __launch_bounds__(512, 2) void gram_kernel(
    const unsigned short* __restrict__ rep, double* __restrict__ ws)
{
    __shared__ unsigned short sA[2][2][128 * 64];  // [buf][half] 64 KB
    __shared__ unsigned short sB[2][2][128 * 64];  // 64 KB
    __shared__ float red[16];

    const int tid  = threadIdx.x;
    const int wave = tid >> 6, lane = tid & 63;
    const int wm = wave >> 2, wn = wave & 3;       // 2 x 4 waves
    const int m = lane & 15, quad = lane >> 4;     // MFMA fragment coords
    // Bank swizzle: rows are 128 B (stride = 32 banks) -> XOR row低bits into
    // the 16B-slot bits. row%8 == m%8 for every fragment read -> lane-constant.
    const int swz   = (m & 7) << 4;
    const int koff0 = (0  + quad * 16) ^ swz;
    const int koff1 = (64 + quad * 16) ^ swz;

    // Triangular block decode: u -> (bi, bj), bj >= bi.
    const int u = blockIdx.x;
    int bi = (int)((2.0f * NT + 1.0f
                    - sqrtf((2.0f * NT + 1.0f) * (2.0f * NT + 1.0f) - 8.0f * (float)u)) * 0.5f);
    while ((bi + 1) * NT - ((bi + 1) * bi) / 2 <= u) ++bi;
    while (bi * NT - (bi * (bi - 1)) / 2 > u) --bi;
    const int bj = bi + (u - (bi * NT - (bi * (bi - 1)) / 2));
    const int i0 = bi * 256, j0 = bj * 256;

    floatx4 acc[8][4];
    #pragma unroll
    for (int x = 0; x < 8; ++x)
        #pragma unroll
        for (int y = 0; y < 4; ++y)
            #pragma unroll
            for (int e = 0; e < 4; ++e) acc[x][y][e] = 0.0f;

    bf16x8 a[4][2], bL[2][2], bR[2][2];

    // ---- Prologue: tile0 complete + tile1 B-halves (matches steady state) ----
    stage_half(rep, i0,       0,  sA[0][0], tid);
    stage_half(rep, i0 + 128, 0,  sA[0][1], tid);
    stage_half(rep, j0,       0,  sB[0][0], tid);
    stage_half(rep, j0 + 128, 0,  sB[0][1], tid);
    stage_half(rep, j0,       64, sB[1][0], tid);
    stage_half(rep, j0 + 128, 64, sB[1][1], tid);
    WAIT_VM(4);                       // tile0 landed; tile1 B's (4 loads) in flight
    __builtin_amdgcn_s_barrier();
    __builtin_amdgcn_sched_barrier(0);

    // ---- Main loop: iterations compute tiles (T, T+1), stage (T+1 A, T+2, T+3 B)
    int kA1 = 64, kT2 = 128, kT3 = 192;
    for (int it = 0; it < 3; ++it) {
        // ph1: reads A(mh0)+B-left of buf0; stage A0(T+1)->buf1
        LOAD_A(0, 0); LOAD_B(0, 0, bL);
        stage_half(rep, i0, kA1, sA[1][0], tid);
        PH_BAR1(); MFMA_Q(0, 0, bL); PH_BAR2();
        // ph2: reads B-right buf0; stage A1(T+1)->buf1
        LOAD_B(0, 1, bR);
        stage_half(rep, i0 + 128, kA1, sA[1][1], tid);
        PH_BAR1(); MFMA_Q(0, 1, bR); PH_BAR2();
        // ph3: reads A(mh1) buf0; stage B0(T+2)->buf0 (B buf0 free after ph2)
        LOAD_A(0, 1);
        stage_half(rep, j0, kT2, sB[0][0], tid);
        PH_BAR1(); MFMA_Q(1, 1, bR); PH_BAR2();
        // ph4: stage B1(T+2)->buf0; counted wait: tile T+1 landed (4 loads allowed)
        stage_half(rep, j0 + 128, kT2, sB[0][1], tid);
        WAIT_VM(4);
        PH_BAR1(); MFMA_Q(1, 0, bL); PH_BAR2();
        // ph5: reads A(mh0)+B-left of buf1; stage A0(T+2)->buf0
        LOAD_A(1, 0); LOAD_B(1, 0, bL);
        stage_half(rep, i0, kT2, sA[0][0], tid);
        PH_BAR1(); MFMA_Q(0, 0, bL); PH_BAR2();
        // ph6: reads B-right buf1; stage A1(T+2)->buf0
        LOAD_B(1, 1, bR);
        stage_half(rep, i0 + 128, kT2, sA[0][1], tid);
        PH_BAR1(); MFMA_Q(0, 1, bR); PH_BAR2();
        // ph7: reads A(mh1) buf1; stage B0(T+3)->buf1
        LOAD_A(1, 1);
        stage_half(rep, j0, kT3, sB[1][0], tid);
        PH_BAR1(); MFMA_Q(1, 1, bR); PH_BAR2();
        // ph8: stage B1(T+3)->buf1; counted wait: tile T+2 landed
        stage_half(rep, j0 + 128, kT3, sB[1][1], tid);
        WAIT_VM(4);
        PH_BAR1(); MFMA_Q(1, 0, bL); PH_BAR2();
        kA1 += 128; kT2 += 128; kT3 += 128;
    }

    // ---- Epilogue: tiles 6 (buf0), 7 (buf1); finish staging tile7 A-halves ----
    LOAD_A(0, 0); LOAD_B(0, 0, bL);
    stage_half(rep, i0, 448, sA[1][0], tid);
    PH_BAR1(); MFMA_Q(0, 0, bL); PH_BAR2();
    LOAD_B(0, 1, bR);
    stage_half(rep, i0 + 128, 448, sA[1][1], tid);
    PH_BAR1(); MFMA_Q(0, 1, bR); PH_BAR2();
    LOAD_A(0, 1);
    PH_BAR1(); MFMA_Q(1, 1, bR); PH_BAR2();
    WAIT_VM(0);                       // drain: tile7 fully landed
    PH_BAR1(); MFMA_Q(1, 0, bL); PH_BAR2();
    LOAD_A(1, 0); LOAD_B(1, 0, bL);
    PH_BAR1(); MFMA_Q(0, 0, bL); PH_BAR2();
    LOAD_B(1, 1, bR);
    PH_BAR1(); MFMA_Q(0, 1, bR); PH_BAR2();
    LOAD_A(1, 1);
    PH_BAR1(); MFMA_Q(1, 1, bR); PH_BAR2();
    MFMA_Q(1, 0, bL);                 // last phase: registers only, no barrier

    // ---- Fused epilogue: exp(sim/tau) = exp2(sim * 2/ln2); band + total sums ----
    float s_all = 0.0f, s_pos = 0.0f;
    const float LOG2E2 = 2.885390081777927f;  // 2 / ln(2)
    #pragma unroll
    for (int mi = 0; mi < 8; ++mi) {
        const int ibase = i0 + wm * 128 + mi * 16 + quad * 4;
        #pragma unroll
        for (int nj = 0; nj < 4; ++nj) {
            const int j = j0 + wn * 64 + nj * 16 + m;
            const floatx4 v = acc[mi][nj];
            #pragma unroll
            for (int e = 0; e < 4; ++e) {
                const int i = ibase + e;
                const float ex = exp2f(v[e] * LOG2E2);
                if (i != j) s_all += ex;
                const int d = j - i;  // upper triangle: band offsets positive
                if (d == 2048 || d == 4096 || d == 6144) s_pos += ex;
            }
        }
    }
    #pragma unroll
    for (int off = 32; off; off >>= 1) {
        s_all += __shfl_xor(s_all, off, 64);
        s_pos += __shfl_xor(s_pos, off, 64);
    }
    if (lane == 0) { red[wave] = s_all; red[8 + wave] = s_pos; }
    __syncthreads();
    if (tid == 0) {
        float ta = 0.0f, tp = 0.0f;
        #pragma unroll
        for (int w2 = 0; w2 < 8; ++w2) { ta += red[w2]; tp += red[8 + w2]; }
        const float wgt = (bi == bj) ? 1.0f : 2.0f;  // off-diag covers transpose half
        atomicAdd(&ws[0], (double)(ta * wgt));
        atomicAdd(&ws[1], (double)(tp * wgt));
    }
}

__global__ void finalize_kernel(const double* __restrict__ ws, float* __restrict__ out) {
    const double nom = ws[1];
    const double den = ws[0] - nom;
    out[0] = (float)(-log(nom / den) / (double)NROWS);
}

extern "C" void kernel_launch(void* const* d_in, const int* in_sizes, int n_in,
                              void* d_out, int out_size, void* d_ws, size_t ws_size,
                              hipStream_t stream) {
    const float* emb_i = (const float*)d_in[0];
    const float* emb_j = (const float*)d_in[1];
    float* out = (float*)d_out;
    double* ws = (double*)d_ws;                                   // 2 accumulators
    unsigned short* rep = (unsigned short*)((char*)d_ws + 256);   // bf16 [8192][512]

    hipLaunchKernelGGL(normalize_kernel, dim3(NROWS / 4), dim3(256), 0, stream,
                       emb_i, emb_j, rep, ws);
    hipLaunchKernelGGL(gram_kernel, dim3(NTRI), dim3(512), 0, stream, rep, ws);
    hipLaunchKernelGGL(finalize_kernel, dim3(1), dim3(1), 0, stream, ws, out);
}